// Round 7
// baseline (196.534 us; speedup 1.0000x reference)
//
#include <hip/hip_runtime.h>

// Median filter (k=22, REFLECT) + blend, NHWC (2,224,224,3) fp32.
// One wave per 8 consecutive-x pixels (stride-1 warm start). Window (484) in
// 8 regs/lane, ballot counting. Newton-probed threshold search (uniform-
// density step 1/484, bracket-guarded) runs until #(v<t) == RANK EXACTLY, so
// the terminal step is a single masked wave-max reduce (no peel loop).
// Duplicate/degenerate cases use a snap-walk (reduce + recount per step,
// strictly monotone count) -> exact for any input incl. REFLECT duplicates.
// Block = 64 (1 wave) for tight CU packing (edge waves are slower; 4-wave
// blocks held occupancy at ~64%).

#define HH 224
#define WW 224
#define CHN 3
#define KK 22
#define PT 10            // pad top/left; bottom/right = 11
#define AREA (KK * KK)   // 484
#define RANK 242         // median = 242nd smallest (1-indexed)
#define PXW 8
#define XGS (WW / PXW)   // 28
#define INVD (1.0f / 484.0f)

#define INFF  __int_as_float(0x7f800000)
#define NINFF __int_as_float(0xff800000)

__device__ __forceinline__ int reflect224(int g) {
    int a = abs(g);
    return min(a, 2 * (HH - 1) - a);
}

__device__ __forceinline__ int count8(const float v[8], float t) {
    int c = 0;
#pragma unroll
    for (int i = 0; i < 8; ++i)
        c += __popcll(__ballot(v[i] < t));
    return c;
}

// max over {v[i] : v[i] < t}, result in all lanes
__device__ __forceinline__ float wmax_below(const float v[8], float t) {
    float m = NINFF;
#pragma unroll
    for (int i = 0; i < 8; ++i)
        m = fmaxf(m, (v[i] < t) ? v[i] : NINFF);
#pragma unroll
    for (int off = 32; off > 0; off >>= 1)
        m = fmaxf(m, __shfl_xor(m, off, 64));
    return m;
}

// min over {v[i] : v[i] >= t}, result in all lanes
__device__ __forceinline__ float wmin_above(const float v[8], float t) {
    float m = INFF;
#pragma unroll
    for (int i = 0; i < 8; ++i)
        m = fminf(m, (v[i] >= t) ? v[i] : INFF);
#pragma unroll
    for (int off = 32; off > 0; off >>= 1)
        m = fminf(m, __shfl_xor(m, off, 64));
    return m;
}

__device__ __forceinline__ void gather(float v[8], const float* __restrict__ img,
                                       const int voff[8], int lane, int x) {
    if (x >= PT && x <= WW - 1 - (KK - 1 - PT)) {      // interior: x in [10,212]
        const float* base = img + (x - PT) * CHN;      // wave-uniform base
#pragma unroll
        for (int i = 0; i < 8; ++i) v[i] = base[voff[i]];
    } else {
#pragma unroll
        for (int i = 0; i < 8; ++i) {
            int s   = i * 64 + lane;
            int se  = min(s, AREA - 1);
            int row = se / KK;
            int col = se - row * KK;
            int gy672 = voff[i] - col * CHN;
            int gx = reflect224(x - PT + col);
            v[i] = img[gy672 + gx * CHN];
        }
    }
    v[7] = (lane < AREA - 448) ? v[7] : INFF;          // slots >= 484 -> +INF
}

__global__ __launch_bounds__(64)
void median_blend_kernel(const float* __restrict__ in,
                         const float* __restrict__ blend,
                         float* __restrict__ out) {
    const int lane = threadIdx.x;
    const int wg = blockIdx.x;                  // one wave per block
    // wg = ((b*CHN + c)*HH + y)*XGS + xg
    const int xg = wg % XGS;
    const int t1 = wg / XGS;
    const int y  = t1 % HH;
    const int t2 = t1 / HH;
    const int c  = t2 % CHN;
    const int b  = t2 / CHN;

    const float f = blend[0];
    const float* img  = in  + (size_t)b * (HH * WW * CHN) + c;
    float*       outp = out + (size_t)b * (HH * WW * CHN) + c;

    // per-wave lane constants: voff = gy*672 + col*3 (vertical reflect baked in)
    int voff[8];
#pragma unroll
    for (int i = 0; i < 8; ++i) {
        int s   = i * 64 + lane;
        int se  = min(s, AREA - 1);
        int row = se / KK;
        int col = se - row * KK;
        int gy  = reflect224(y - PT + row);
        voff[i] = gy * (WW * CHN) + col * CHN;
    }

    const int x0 = xg * PXW;
    float tprev = 0.5f;

#pragma unroll 1
    for (int j = 0; j < PXW; ++j) {
        const int x = x0 + j;

        float v[8];
        gather(v, img, voff, lane, x);

        // ---- Newton-probed search to exact count (warm-started) ----
        float t = tprev;
        int C = count8(v, t);
        float lo = 0.0f, hi = 1.0f;
        int clo = 0, chi = AREA;
        bool exact = (C == RANK);
#pragma unroll 1
        for (int it = 0; it < 12 && !exact; ++it) {
            int d = C - RANK;
            if (d > 0) { hi = t; chi = C; }
            else       { lo = t; clo = C; }
            // Newton step at uniform density; bracket-guarded
            float tn = t + (float)(RANK - C) * INVD;
            if (!(tn > lo && tn < hi)) {
                tn = lo + (hi - lo) * (float)(RANK - clo) *
                     __builtin_amdgcn_rcpf((float)(chi - clo));
                if (!(tn > lo && tn < hi)) {
                    tn = 0.5f * (lo + hi);
                    if (!(tn > lo && tn < hi)) break;   // degenerate bracket
                }
            }
            t = tn;
            C = count8(v, t);
            exact = (C == RANK);
        }

        // ---- terminal ----
        float med;
        if (exact) {
            med = wmax_below(v, t);            // max of the RANK smallest
        } else {
            // snap-walk: strictly monotone count per step; exact & bounded.
            med = t;                           // always overwritten
#pragma unroll 1
            for (int r = 0; r < 300; ++r) {
                int d = C - RANK;
                if (d == 0) { med = wmax_below(v, t); break; }
                if (d > 0) {
                    float M = wmax_below(v, t);        // largest below t
                    int C2 = count8(v, M);             // #{v < M}  (= C - mult(M))
                    if (C2 < RANK) { med = M; break; } // M is rank-RANK value
                    t = M; C = C2;
                } else {
                    float m = wmin_above(v, t);        // smallest >= t
                    float tn = __int_as_float(__float_as_int(m) + 1); // nextup
                    int C2 = count8(v, tn);            // #{v <= m}
                    if (C2 >= RANK) { med = m; break; }
                    t = tn; C = C2;
                }
            }
        }
        tprev = med;                            // warm start for next pixel

        // ---- blend + store ----
        const float xc = img[y * (WW * CHN) + x * CHN];
        if (lane == 0)
            outp[y * (WW * CHN) + x * CHN] = med + f * (xc - med);
    }
}

extern "C" void kernel_launch(void* const* d_in, const int* in_sizes, int n_in,
                              void* d_out, int out_size, void* d_ws, size_t ws_size,
                              hipStream_t stream) {
    const float* in    = (const float*)d_in[0];
    const float* blend = (const float*)d_in[1];
    float* out = (float*)d_out;

    const int nwaves = 2 * CHN * HH * XGS;    // 37632, one wave per block
    median_blend_kernel<<<nwaves, 64, 0, stream>>>(in, blend, out);
}